// Round 17
// baseline (128.183 us; speedup 1.0000x reference)
//
#include <hip/hip_runtime.h>

constexpr int EMB_DIM   = 300;
constexpr int HIDDEN    = 256;
constexpr int OUT_DIM   = 3;
constexpr int SEQ       = 128;
constexpr int N_ASPECTS = 8;
constexpr int TILE      = 32;    // bucket padding granularity (multiple of MTILE)
constexpr int MTILE     = 4;     // samples per fused block (2 waves x 2)

// ---------------------------------------------------------------------------
// bf16 helpers (RNE)
// ---------------------------------------------------------------------------
__device__ __forceinline__ unsigned int bfbits(float f) {
  unsigned int u = __float_as_uint(f);
  return (u + 0x7fffu + ((u >> 16) & 1u)) >> 16;
}
__device__ __forceinline__ unsigned int pack2(float lo, float hi) {
  return bfbits(lo) | (bfbits(hi) << 16);
}
__device__ __forceinline__ float blo(unsigned int u) { return __uint_as_float(u << 16); }
__device__ __forceinline__ float bhi(unsigned int u) { return __uint_as_float(u & 0xffff0000u); }

// ---------------------------------------------------------------------------
// Fused prep: block 0 = deterministic counting-sort bucketing (pad to TILE,
// -1 = padding); blocks 1..N = fp32->bf16 conversion of the embedding table
// (90 MB stream) and W1 (2.4 MB) in one grid-stride range.
// ---------------------------------------------------------------------------
__global__ __launch_bounds__(1024) void prep_kernel(
    const float* __restrict__ emb, unsigned int* __restrict__ emb16, int n8,
    const float* __restrict__ W1, unsigned int* __restrict__ w16, int nw8,
    const int* __restrict__ aspect, int B, int* __restrict__ perm, int nperm) {
  const int t = threadIdx.x;

  if (blockIdx.x != 0) {
    int i = (blockIdx.x - 1) * 1024 + t;
    const int stride = (gridDim.x - 1) * 1024;
    const int total8 = n8 + nw8;
    for (; i < total8; i += stride) {
      const float4* p;
      unsigned int* dst;
      int k;
      if (i < n8) { p = (const float4*)emb + (size_t)i * 2;        dst = emb16; k = i; }
      else        { p = (const float4*)W1  + (size_t)(i - n8) * 2; dst = w16;   k = i - n8; }
      float4 a = p[0], b = p[1];
      uint4 o;
      o.x = pack2(a.x, a.y); o.y = pack2(a.z, a.w);
      o.z = pack2(b.x, b.y); o.w = pack2(b.z, b.w);
      ((uint4*)dst)[k] = o;
    }
    return;
  }

  const int lane = t & 63, wave = t >> 6;          // 16 waves
  __shared__ int wcnt[16][N_ASPECTS];
  __shared__ int cur[16][N_ASPECTS];

  for (int i = t; i < nperm; i += 1024) perm[i] = -1;

  int my_a[8];
  int cnt[N_ASPECTS];
#pragma unroll
  for (int q = 0; q < N_ASPECTS; ++q) cnt[q] = 0;
#pragma unroll
  for (int k = 0; k < 8; ++k) {
    int s = t + k * 1024;
    int a = (s < B) ? aspect[s] : -1;
    my_a[k] = a;
#pragma unroll
    for (int q = 0; q < N_ASPECTS; ++q) cnt[q] += (a == q);
  }
#pragma unroll
  for (int q = 0; q < N_ASPECTS; ++q) {
    int c = cnt[q];
    for (int off = 32; off > 0; off >>= 1) c += __shfl_down(c, off);
    if (lane == 0) wcnt[wave][q] = c;
  }
  __syncthreads();
  if (t == 0) {
    int base = 0;
    for (int q = 0; q < N_ASPECTS; ++q) {
      int tot = 0;
      for (int w = 0; w < 16; ++w) { cur[w][q] = base + tot; tot += wcnt[w][q]; }
      base += ((tot + TILE - 1) / TILE) * TILE;
    }
  }
  __syncthreads();

#pragma unroll
  for (int k = 0; k < 8; ++k) {
    int a = my_a[k];
    int s = t + k * 1024;
#pragma unroll
    for (int q = 0; q < N_ASPECTS; ++q) {
      unsigned long long m = __ballot(a == q);
      if (a == q) {
        int rank = __popcll(m & ((1ull << lane) - 1ull));
        int pos = cur[wave][q] + rank;
        perm[pos] = s;
        if (rank == __popcll(m) - 1) cur[wave][q] = pos + 1;
      }
    }
  }
}

// ---------------------------------------------------------------------------
// Fused pool+MLP, wave-decoupled: block = 4 bucketed same-aspect samples,
// 2 waves; wave w pools samples {2w, 2w+1} interleaved (the 6x-confirmed
// best gather shape), writes pooled x to WAVE-PRIVATE LDS rows, then runs
// the full-K MLP for its own 2 samples with NO barrier and NO exchange.
// Finer blocks (8/CU) interleave pool- and MLP-phase waves across the CU;
// no straggler coupling. All register indices static (rule #20).
// ---------------------------------------------------------------------------
__global__ __launch_bounds__(128) void fused_kernel(
    const int* __restrict__ ids, const unsigned short* __restrict__ emb16,
    const int* __restrict__ aspect, const int* __restrict__ perm,
    const unsigned short* __restrict__ w16, const float* __restrict__ b1,
    const float* __restrict__ W2, const float* __restrict__ b2,
    float* __restrict__ out) {
  const int t = threadIdx.x;
  const int wave = t >> 6, lane = t & 63;
  const int start = blockIdx.x * MTILE;

  __shared__ int            ss[MTILE];
  __shared__ unsigned short sid[MTILE][SEQ];    // sorted token ids, 1 KB
  __shared__ float          xs[MTILE][EMB_DIM]; // pooled x rows, 4.8 KB

  if (t < MTILE) ss[t] = perm[start + t];
  __syncthreads();
  const int s0 = ss[0];
  if (s0 < 0) return;                        // fully-padded block
  const int a = aspect[s0];

  // ---- pool phase: this wave's two samples, interleaved ----
  const int sa = 2 * wave, sb = 2 * wave + 1;
  const int msA = __builtin_amdgcn_readfirstlane(ss[sa]);
  const int msB = __builtin_amdgcn_readfirstlane(ss[sb]);
  const int ma = msA < 0 ? s0 : msA;
  const int mb = msB < 0 ? s0 : msB;

  int r0 = ids[(size_t)ma * SEQ + lane];
  int r1 = ids[(size_t)ma * SEQ + lane + 64];
  int r2 = ids[(size_t)mb * SEQ + lane];
  int r3 = ids[(size_t)mb * SEQ + lane + 64];

  // two interleaved bitonic sorts (128 ids each); sort bugs can only cost
  // locality, never correctness (compare-exchange preserves the multiset)
#pragma unroll
  for (int k = 2; k <= 128; k <<= 1) {
#pragma unroll
    for (int j = k >> 1; j >= 1; j >>= 1) {
      if (j == 64) {
        int lo0 = min(r0, r1), hi0 = max(r0, r1);
        int lo1 = min(r2, r3), hi1 = max(r2, r3);
        r0 = lo0; r1 = hi0; r2 = lo1; r3 = hi1;
      } else {
        const bool up0 = ((lane & k) == 0);
        const bool up1 = (((lane + 64) & k) == 0);
        const bool side = ((lane & j) == 0);
        int o0 = __shfl_xor(r0, j);
        int o1 = __shfl_xor(r1, j);
        int o2 = __shfl_xor(r2, j);
        int o3 = __shfl_xor(r3, j);
        r0 = (side == up0) ? min(r0, o0) : max(r0, o0);
        r1 = (side == up1) ? min(r1, o1) : max(r1, o1);
        r2 = (side == up0) ? min(r2, o2) : max(r2, o2);
        r3 = (side == up1) ? min(r3, o3) : max(r3, o3);
      }
    }
  }

  sid[sa][lane]      = (unsigned short)r0;
  sid[sa][lane + 64] = (unsigned short)r1;
  sid[sb][lane]      = (unsigned short)r2;
  sid[sb][lane + 64] = (unsigned short)r3;
  // same-wave LDS RAW: compiler inserts lgkmcnt waits; no barrier needed

  float p0 = 0.f, p1 = 0.f, p2 = 0.f, p3 = 0.f;   // sample a, dims 4l..
  float q0 = 0.f, q1 = 0.f, q2 = 0.f, q3 = 0.f;   // sample b, dims 4l..
  float ta0 = 0.f, ta1 = 0.f, ta2 = 0.f, ta3 = 0.f; // sample a tail
  float tb0 = 0.f, tb1 = 0.f, tb2 = 0.f, tb3 = 0.f; // sample b tail
  const bool tail = (lane < 11);

#pragma unroll 4
  for (int s = 0; s < SEQ; ++s) {
    const uint2* __restrict__ ra =
        (const uint2*)(emb16 + (size_t)sid[sa][s] * EMB_DIM);
    const uint2* __restrict__ rb =
        (const uint2*)(emb16 + (size_t)sid[sb][s] * EMB_DIM);
    uint2 va = ra[lane];
    uint2 vb = rb[lane];
    p0 += blo(va.x); p1 += bhi(va.x); p2 += blo(va.y); p3 += bhi(va.y);
    q0 += blo(vb.x); q1 += bhi(vb.x); q2 += blo(vb.y); q3 += bhi(vb.y);
    if (tail) {
      uint2 wa = ra[64 + lane];
      uint2 wb = rb[64 + lane];
      ta0 += blo(wa.x); ta1 += bhi(wa.x); ta2 += blo(wa.y); ta3 += bhi(wa.y);
      tb0 += blo(wb.x); tb1 += bhi(wb.x); tb2 += blo(wb.y); tb3 += bhi(wb.y);
    }
  }

  const float sc = 1.0f / (float)SEQ;
  *(float4*)&xs[sa][4 * lane] = make_float4(p0 * sc, p1 * sc, p2 * sc, p3 * sc);
  *(float4*)&xs[sb][4 * lane] = make_float4(q0 * sc, q1 * sc, q2 * sc, q3 * sc);
  if (tail) {
    *(float4*)&xs[sa][256 + 4 * lane] =
        make_float4(ta0 * sc, ta1 * sc, ta2 * sc, ta3 * sc);
    *(float4*)&xs[sb][256 + 4 * lane] =
        make_float4(tb0 * sc, tb1 * sc, tb2 * sc, tb3 * sc);
  }
  // NO barrier: this wave's MLP reads only xs[sa], xs[sb] (wave-private).

  // ---- MLP phase: this wave's 2 samples, full K, no exchange ----
  const unsigned short* __restrict__ w1r =
      w16 + (size_t)a * EMB_DIM * HIDDEN + 4 * lane;
  const float4 bb = ((const float4*)(b1 + a * HIDDEN))[lane];
  float4 acc0 = bb, acc1 = bb;

#pragma unroll 2
  for (int d = 0; d < EMB_DIM; d += 4) {
    float4 xv0 = *(const float4*)&xs[sa][d];
    float4 xv1 = *(const float4*)&xs[sb][d];
#pragma unroll
    for (int dd = 0; dd < 4; ++dd) {
      const uint2 wv = *(const uint2*)(w1r + (size_t)(d + dd) * HIDDEN);
      const float w0 = blo(wv.x), w1v = bhi(wv.x);
      const float w2v = blo(wv.y), w3v = bhi(wv.y);
      const float x0 = dd == 0 ? xv0.x : dd == 1 ? xv0.y : dd == 2 ? xv0.z : xv0.w;
      const float x1 = dd == 0 ? xv1.x : dd == 1 ? xv1.y : dd == 2 ? xv1.z : xv1.w;
      acc0.x = fmaf(x0, w0,  acc0.x);
      acc0.y = fmaf(x0, w1v, acc0.y);
      acc0.z = fmaf(x0, w2v, acc0.z);
      acc0.w = fmaf(x0, w3v, acc0.w);
      acc1.x = fmaf(x1, w0,  acc1.x);
      acc1.y = fmaf(x1, w1v, acc1.y);
      acc1.z = fmaf(x1, w2v, acc1.z);
      acc1.w = fmaf(x1, w3v, acc1.w);
    }
  }

  // layer 2: cols j = 4*lane..4*lane+3, k = 0..2
  const float4* __restrict__ w2p =
      (const float4*)(W2 + (size_t)a * HIDDEN * OUT_DIM + lane * 12);
  const float4 w2a = w2p[0];   // j0k0 j0k1 j0k2 j1k0
  const float4 w2b = w2p[1];   // j1k1 j1k2 j2k0 j2k1
  const float4 w2c = w2p[2];   // j2k2 j3k0 j3k1 j3k2

  const float ha0 = fmaxf(acc0.x, 0.f), ha1 = fmaxf(acc0.y, 0.f);
  const float ha2 = fmaxf(acc0.z, 0.f), ha3 = fmaxf(acc0.w, 0.f);
  const float hb0 = fmaxf(acc1.x, 0.f), hb1 = fmaxf(acc1.y, 0.f);
  const float hb2 = fmaxf(acc1.z, 0.f), hb3 = fmaxf(acc1.w, 0.f);

  float pa0 = fmaf(ha0, w2a.x, fmaf(ha1, w2a.w, fmaf(ha2, w2b.z, ha3 * w2c.y)));
  float pa1 = fmaf(ha0, w2a.y, fmaf(ha1, w2b.x, fmaf(ha2, w2b.w, ha3 * w2c.z)));
  float pa2 = fmaf(ha0, w2a.z, fmaf(ha1, w2b.y, fmaf(ha2, w2c.x, ha3 * w2c.w)));
  float pb0 = fmaf(hb0, w2a.x, fmaf(hb1, w2a.w, fmaf(hb2, w2b.z, hb3 * w2c.y)));
  float pb1 = fmaf(hb0, w2a.y, fmaf(hb1, w2b.x, fmaf(hb2, w2b.w, hb3 * w2c.z)));
  float pb2 = fmaf(hb0, w2a.z, fmaf(hb1, w2b.y, fmaf(hb2, w2c.x, hb3 * w2c.w)));

#pragma unroll
  for (int off = 32; off > 0; off >>= 1) {
    pa0 += __shfl_down(pa0, off);
    pa1 += __shfl_down(pa1, off);
    pa2 += __shfl_down(pa2, off);
    pb0 += __shfl_down(pb0, off);
    pb1 += __shfl_down(pb1, off);
    pb2 += __shfl_down(pb2, off);
  }

  if (lane == 0) {
    const float g0 = b2[a * OUT_DIM + 0];
    const float g1 = b2[a * OUT_DIM + 1];
    const float g2 = b2[a * OUT_DIM + 2];
    if (msA >= 0) {
      float* o = out + (size_t)msA * OUT_DIM;
      o[0] = pa0 + g0; o[1] = pa1 + g1; o[2] = pa2 + g2;
    }
    if (msB >= 0) {
      float* o = out + (size_t)msB * OUT_DIM;
      o[0] = pb0 + g0; o[1] = pb1 + g1; o[2] = pb2 + g2;
    }
  }
}

// ---------------------------------------------------------------------------
extern "C" void kernel_launch(void* const* d_in, const int* in_sizes, int n_in,
                              void* d_out, int out_size, void* d_ws, size_t ws_size,
                              hipStream_t stream) {
  const int*   ids    = (const int*)d_in[0];
  const int*   aspect = (const int*)d_in[1];
  const float* emb    = (const float*)d_in[2];
  const float* W1     = (const float*)d_in[3];
  const float* b1     = (const float*)d_in[4];
  const float* W2     = (const float*)d_in[5];
  const float* b2     = (const float*)d_in[6];
  float*       out    = (float*)d_out;

  const int B     = in_sizes[1];
  const int nemb  = in_sizes[2];               // 15,000,000 (div by 8)
  const int nw1   = in_sizes[3];               // 614,400 (div by 8)
  const int nblk  = (B + TILE - 1) / TILE + N_ASPECTS;
  const int nperm = nblk * TILE;               // multiple of 32 (and of MTILE)

  // workspace: [perm: nperm i32][emb16: nemb bf16][w16: nw1 bf16]
  int* perm = (int*)d_ws;
  unsigned short* emb16 =
      (unsigned short*)((char*)perm + (((size_t)nperm * 4 + 15) & ~(size_t)15));
  unsigned short* w16 = emb16 + (size_t)nemb;

  prep_kernel<<<513, 1024, 0, stream>>>(emb, (unsigned int*)emb16, nemb / 8,
                                        W1, (unsigned int*)w16, nw1 / 8,
                                        aspect, B, perm, nperm);
  fused_kernel<<<nperm / MTILE, 128, 0, stream>>>(ids, emb16, aspect, perm,
                                                  w16, b1, W2, b2, out);
}

// Round 18
// 120.481 us; speedup vs baseline: 1.0639x; 1.0639x over previous
//
#include <hip/hip_runtime.h>

constexpr int EMB_DIM   = 300;
constexpr int HIDDEN    = 256;
constexpr int OUT_DIM   = 3;
constexpr int SEQ       = 128;
constexpr int N_ASPECTS = 8;
constexpr int TILE      = 32;    // bucket padding granularity (multiple of MTILE)
constexpr int MTILE     = 8;     // samples per fused block (4 waves x 2)

// ---------------------------------------------------------------------------
// bf16 helpers (RNE)
// ---------------------------------------------------------------------------
__device__ __forceinline__ unsigned int bfbits(float f) {
  unsigned int u = __float_as_uint(f);
  return (u + 0x7fffu + ((u >> 16) & 1u)) >> 16;
}
__device__ __forceinline__ unsigned int pack2(float lo, float hi) {
  return bfbits(lo) | (bfbits(hi) << 16);
}
__device__ __forceinline__ float blo(unsigned int u) { return __uint_as_float(u << 16); }
__device__ __forceinline__ float bhi(unsigned int u) { return __uint_as_float(u & 0xffff0000u); }

// ---------------------------------------------------------------------------
// Fused prep: block 0 = deterministic counting-sort bucketing (pad to TILE,
// -1 = padding); blocks 1..N = fp32->bf16 conversion of the embedding table
// (90 MB stream) and W1 (2.4 MB) in one grid-stride range.
// ---------------------------------------------------------------------------
__global__ __launch_bounds__(1024) void prep_kernel(
    const float* __restrict__ emb, unsigned int* __restrict__ emb16, int n8,
    const float* __restrict__ W1, unsigned int* __restrict__ w16, int nw8,
    const int* __restrict__ aspect, int B, int* __restrict__ perm, int nperm) {
  const int t = threadIdx.x;

  if (blockIdx.x != 0) {
    int i = (blockIdx.x - 1) * 1024 + t;
    const int stride = (gridDim.x - 1) * 1024;
    const int total8 = n8 + nw8;
    for (; i < total8; i += stride) {
      const float4* p;
      unsigned int* dst;
      int k;
      if (i < n8) { p = (const float4*)emb + (size_t)i * 2;        dst = emb16; k = i; }
      else        { p = (const float4*)W1  + (size_t)(i - n8) * 2; dst = w16;   k = i - n8; }
      float4 a = p[0], b = p[1];
      uint4 o;
      o.x = pack2(a.x, a.y); o.y = pack2(a.z, a.w);
      o.z = pack2(b.x, b.y); o.w = pack2(b.z, b.w);
      ((uint4*)dst)[k] = o;
    }
    return;
  }

  const int lane = t & 63, wave = t >> 6;          // 16 waves
  __shared__ int wcnt[16][N_ASPECTS];
  __shared__ int cur[16][N_ASPECTS];

  for (int i = t; i < nperm; i += 1024) perm[i] = -1;

  int my_a[8];
  int cnt[N_ASPECTS];
#pragma unroll
  for (int q = 0; q < N_ASPECTS; ++q) cnt[q] = 0;
#pragma unroll
  for (int k = 0; k < 8; ++k) {
    int s = t + k * 1024;
    int a = (s < B) ? aspect[s] : -1;
    my_a[k] = a;
#pragma unroll
    for (int q = 0; q < N_ASPECTS; ++q) cnt[q] += (a == q);
  }
#pragma unroll
  for (int q = 0; q < N_ASPECTS; ++q) {
    int c = cnt[q];
    for (int off = 32; off > 0; off >>= 1) c += __shfl_down(c, off);
    if (lane == 0) wcnt[wave][q] = c;
  }
  __syncthreads();
  if (t == 0) {
    int base = 0;
    for (int q = 0; q < N_ASPECTS; ++q) {
      int tot = 0;
      for (int w = 0; w < 16; ++w) { cur[w][q] = base + tot; tot += wcnt[w][q]; }
      base += ((tot + TILE - 1) / TILE) * TILE;
    }
  }
  __syncthreads();

#pragma unroll
  for (int k = 0; k < 8; ++k) {
    int a = my_a[k];
    int s = t + k * 1024;
#pragma unroll
    for (int q = 0; q < N_ASPECTS; ++q) {
      unsigned long long m = __ballot(a == q);
      if (a == q) {
        int rank = __popcll(m & ((1ull << lane) - 1ull));
        int pos = cur[wave][q] + rank;
        perm[pos] = s;
        if (rank == __popcll(m) - 1) cur[wave][q] = pos + 1;
      }
    }
  }
}

// ---------------------------------------------------------------------------
// Fused pool+MLP (R14, best-measured): block = 8 bucketed same-aspect
// samples, 4 waves; wave w pools samples {2w, 2w+1} interleaved (4
// independent load streams/wave — the best-measured gather shape). Pooled x
// lives in LDS only. MLP phase after one barrier: split-K, x from LDS,
// bf16 W1. All register-array indices compile-time static (rule #20).
// ---------------------------------------------------------------------------
__global__ __launch_bounds__(256) void fused_kernel(
    const int* __restrict__ ids, const unsigned short* __restrict__ emb16,
    const int* __restrict__ aspect, const int* __restrict__ perm,
    const unsigned short* __restrict__ w16, const float* __restrict__ b1,
    const float* __restrict__ W2, const float* __restrict__ b2,
    float* __restrict__ out) {
  const int t = threadIdx.x;
  const int wave = t >> 6, lane = t & 63;
  const int start = blockIdx.x * MTILE;

  __shared__ int   ss[MTILE];
  __shared__ int   sid[MTILE][SEQ];          // sorted token ids, 4 KB
  __shared__ float xs[MTILE][EMB_DIM + 4];   // pooled x rows
  __shared__ float xch[2][4][64][4];         // MLP partial exchange, 8 KB

  if (t < MTILE) ss[t] = perm[start + t];
  __syncthreads();
  const int s0 = ss[0];
  if (s0 < 0) return;                        // fully-padded block
  const int a = aspect[s0];

  // ---- pool phase: this wave's two samples, interleaved ----
  const int sa = 2 * wave, sb = 2 * wave + 1;
  const int ma = __builtin_amdgcn_readfirstlane(ss[sa] < 0 ? s0 : ss[sa]);
  const int mb = __builtin_amdgcn_readfirstlane(ss[sb] < 0 ? s0 : ss[sb]);

  int r0 = ids[(size_t)ma * SEQ + lane];
  int r1 = ids[(size_t)ma * SEQ + lane + 64];
  int r2 = ids[(size_t)mb * SEQ + lane];
  int r3 = ids[(size_t)mb * SEQ + lane + 64];

  // two interleaved bitonic sorts (128 ids each); sort bugs can only cost
  // locality, never correctness (compare-exchange preserves the multiset)
#pragma unroll
  for (int k = 2; k <= 128; k <<= 1) {
#pragma unroll
    for (int j = k >> 1; j >= 1; j >>= 1) {
      if (j == 64) {
        int lo0 = min(r0, r1), hi0 = max(r0, r1);
        int lo1 = min(r2, r3), hi1 = max(r2, r3);
        r0 = lo0; r1 = hi0; r2 = lo1; r3 = hi1;
      } else {
        const bool up0 = ((lane & k) == 0);
        const bool up1 = (((lane + 64) & k) == 0);
        const bool side = ((lane & j) == 0);
        int o0 = __shfl_xor(r0, j);
        int o1 = __shfl_xor(r1, j);
        int o2 = __shfl_xor(r2, j);
        int o3 = __shfl_xor(r3, j);
        r0 = (side == up0) ? min(r0, o0) : max(r0, o0);
        r1 = (side == up1) ? min(r1, o1) : max(r1, o1);
        r2 = (side == up0) ? min(r2, o2) : max(r2, o2);
        r3 = (side == up1) ? min(r3, o3) : max(r3, o3);
      }
    }
  }

  sid[sa][lane]      = r0;
  sid[sa][lane + 64] = r1;
  sid[sb][lane]      = r2;
  sid[sb][lane + 64] = r3;
  // same-wave LDS RAW below: compiler inserts lgkmcnt waits; no barrier needed

  float p0 = 0.f, p1 = 0.f, p2 = 0.f, p3 = 0.f;   // sample a, dims 4l..
  float q0 = 0.f, q1 = 0.f, q2 = 0.f, q3 = 0.f;   // sample b, dims 4l..
  float ta0 = 0.f, ta1 = 0.f, ta2 = 0.f, ta3 = 0.f; // sample a tail
  float tb0 = 0.f, tb1 = 0.f, tb2 = 0.f, tb3 = 0.f; // sample b tail
  const bool tail = (lane < 11);

#pragma unroll 4
  for (int s = 0; s < SEQ; ++s) {
    const uint2* __restrict__ ra =
        (const uint2*)(emb16 + (size_t)sid[sa][s] * EMB_DIM);
    const uint2* __restrict__ rb =
        (const uint2*)(emb16 + (size_t)sid[sb][s] * EMB_DIM);
    uint2 va = ra[lane];
    uint2 vb = rb[lane];
    p0 += blo(va.x); p1 += bhi(va.x); p2 += blo(va.y); p3 += bhi(va.y);
    q0 += blo(vb.x); q1 += bhi(vb.x); q2 += blo(vb.y); q3 += bhi(vb.y);
    if (tail) {
      uint2 wa = ra[64 + lane];
      uint2 wb = rb[64 + lane];
      ta0 += blo(wa.x); ta1 += bhi(wa.x); ta2 += blo(wa.y); ta3 += bhi(wa.y);
      tb0 += blo(wb.x); tb1 += bhi(wb.x); tb2 += blo(wb.y); tb3 += bhi(wb.y);
    }
  }

  const float sc = 1.0f / (float)SEQ;
  *(float4*)&xs[sa][4 * lane] = make_float4(p0 * sc, p1 * sc, p2 * sc, p3 * sc);
  *(float4*)&xs[sb][4 * lane] = make_float4(q0 * sc, q1 * sc, q2 * sc, q3 * sc);
  if (tail) {
    *(float4*)&xs[sa][256 + 4 * lane] =
        make_float4(ta0 * sc, ta1 * sc, ta2 * sc, ta3 * sc);
    *(float4*)&xs[sb][256 + 4 * lane] =
        make_float4(tb0 * sc, tb1 * sc, tb2 * sc, tb3 * sc);
  }
  __syncthreads();

  // ---- MLP phase (split-K, x from LDS) ----
  const int g = wave >> 1;                 // sample group 0/1 (samples g*4..)
  const int kw = wave & 1;                 // K-half

  int smp[4];
#pragma unroll
  for (int s = 0; s < 4; ++s)
    smp[s] = __builtin_amdgcn_readfirstlane(ss[g * 4 + s]);

  const unsigned short* __restrict__ w1r =
      w16 + (size_t)a * EMB_DIM * HIDDEN + 4 * lane;
  float4 acc[4];
  if (kw == 0) {
    const float4 bb = ((const float4*)(b1 + a * HIDDEN))[lane];
#pragma unroll
    for (int s = 0; s < 4; ++s) acc[s] = bb;
  } else {
#pragma unroll
    for (int s = 0; s < 4; ++s) acc[s] = make_float4(0.f, 0.f, 0.f, 0.f);
  }
  const int d0 = kw ? 160 : 0;
  const int d1 = kw ? EMB_DIM : 160;
#pragma unroll 2
  for (int d = d0; d < d1; d += 4) {
    float4 xv[4];
#pragma unroll
    for (int s = 0; s < 4; ++s) xv[s] = *(const float4*)&xs[g * 4 + s][d];
#pragma unroll
    for (int dd = 0; dd < 4; ++dd) {
      const uint2 wv = *(const uint2*)(w1r + (size_t)(d + dd) * HIDDEN);
      const float w0 = blo(wv.x), w1v = bhi(wv.x);
      const float w2v = blo(wv.y), w3v = bhi(wv.y);
#pragma unroll
      for (int s = 0; s < 4; ++s) {
        const float xsc = dd == 0 ? xv[s].x : dd == 1 ? xv[s].y
                         : dd == 2 ? xv[s].z : xv[s].w;
        acc[s].x = fmaf(xsc, w0,  acc[s].x);
        acc[s].y = fmaf(xsc, w1v, acc[s].y);
        acc[s].z = fmaf(xsc, w2v, acc[s].z);
        acc[s].w = fmaf(xsc, w3v, acc[s].w);
      }
    }
  }

  if (kw == 0) {
    *(float4*)&xch[g][2][lane][0] = acc[2];
    *(float4*)&xch[g][3][lane][0] = acc[3];
  } else {
    *(float4*)&xch[g][0][lane][0] = acc[0];
    *(float4*)&xch[g][1][lane][0] = acc[1];
  }
  __syncthreads();

  const float4* __restrict__ w2p =
      (const float4*)(W2 + (size_t)a * HIDDEN * OUT_DIM + lane * 12);
  const float4 w2a = w2p[0];   // j0k0 j0k1 j0k2 j1k0
  const float4 w2b = w2p[1];   // j1k1 j1k2 j2k0 j2k1
  const float4 w2c = w2p[2];   // j2k2 j3k0 j3k1 j3k2

  float4 own[2];
  int ms[2];
  if (kw == 0) {
    own[0] = acc[0]; own[1] = acc[1];
    ms[0] = smp[0];  ms[1] = smp[1];
  } else {
    own[0] = acc[2]; own[1] = acc[3];
    ms[0] = smp[2];  ms[1] = smp[3];
  }
  const int mys = 2 * kw;                  // LDS base (runtime ok)

  float pp[2][OUT_DIM];
#pragma unroll
  for (int i = 0; i < 2; ++i) {
    const float4 pr = *(const float4*)&xch[g][mys + i][lane][0];
    const float h0 = fmaxf(own[i].x + pr.x, 0.f);
    const float h1 = fmaxf(own[i].y + pr.y, 0.f);
    const float h2 = fmaxf(own[i].z + pr.z, 0.f);
    const float h3 = fmaxf(own[i].w + pr.w, 0.f);
    pp[i][0] = fmaf(h0, w2a.x, fmaf(h1, w2a.w, fmaf(h2, w2b.z, h3 * w2c.y)));
    pp[i][1] = fmaf(h0, w2a.y, fmaf(h1, w2b.x, fmaf(h2, w2b.w, h3 * w2c.z)));
    pp[i][2] = fmaf(h0, w2a.z, fmaf(h1, w2b.y, fmaf(h2, w2c.x, h3 * w2c.w)));
  }
#pragma unroll
  for (int off = 32; off > 0; off >>= 1)
#pragma unroll
    for (int i = 0; i < 2; ++i) {
      pp[i][0] += __shfl_down(pp[i][0], off);
      pp[i][1] += __shfl_down(pp[i][1], off);
      pp[i][2] += __shfl_down(pp[i][2], off);
    }

  if (lane == 0) {
    const float g0 = b2[a * OUT_DIM + 0];
    const float g1 = b2[a * OUT_DIM + 1];
    const float g2 = b2[a * OUT_DIM + 2];
#pragma unroll
    for (int i = 0; i < 2; ++i) {
      if (ms[i] >= 0) {
        float* o = out + (size_t)ms[i] * OUT_DIM;
        o[0] = pp[i][0] + g0;
        o[1] = pp[i][1] + g1;
        o[2] = pp[i][2] + g2;
      }
    }
  }
}

// ---------------------------------------------------------------------------
extern "C" void kernel_launch(void* const* d_in, const int* in_sizes, int n_in,
                              void* d_out, int out_size, void* d_ws, size_t ws_size,
                              hipStream_t stream) {
  const int*   ids    = (const int*)d_in[0];
  const int*   aspect = (const int*)d_in[1];
  const float* emb    = (const float*)d_in[2];
  const float* W1     = (const float*)d_in[3];
  const float* b1     = (const float*)d_in[4];
  const float* W2     = (const float*)d_in[5];
  const float* b2     = (const float*)d_in[6];
  float*       out    = (float*)d_out;

  const int B     = in_sizes[1];
  const int nemb  = in_sizes[2];               // 15,000,000 (div by 8)
  const int nw1   = in_sizes[3];               // 614,400 (div by 8)
  const int nblk  = (B + TILE - 1) / TILE + N_ASPECTS;
  const int nperm = nblk * TILE;               // multiple of 32 (and of MTILE)

  // workspace: [perm: nperm i32][emb16: nemb bf16][w16: nw1 bf16]
  int* perm = (int*)d_ws;
  unsigned short* emb16 =
      (unsigned short*)((char*)perm + (((size_t)nperm * 4 + 15) & ~(size_t)15));
  unsigned short* w16 = emb16 + (size_t)nemb;

  prep_kernel<<<513, 1024, 0, stream>>>(emb, (unsigned int*)emb16, nemb / 8,
                                        W1, (unsigned int*)w16, nw1 / 8,
                                        aspect, B, perm, nperm);
  fused_kernel<<<nperm / MTILE, 256, 0, stream>>>(ids, emb16, aspect, perm,
                                                  w16, b1, W2, b2, out);
}